// Round 8
// baseline (307.871 us; speedup 1.0000x reference)
//
#include <hip/hip_runtime.h>
#include <hip/hip_bf16.h>
#include <math.h>

#define B 128
#define S 1024
#define H 768
#define NH 8
#define DH 96
#define FUSED 2312
#define FPAD 2432            // fused row stride, padded to 19*128
#define KSPLIT 19
#define KCHUNK 128
#define ASL 8                // aspq slices
#define NSL 8                // flash slices per sample
#define FCH 16               // rows per flash chunk
#define SCALE 0.10206207261596575f  // 1/sqrt(96)
#define GELU_C 0.70710678118654752f

__device__ __forceinline__ float dot4(float4 a, float4 b) {
    return a.x * b.x + a.y * b.y + a.z * b.z + a.w * b.w;
}

__device__ __forceinline__ float gelu(float x) {
    return 0.5f * x * (1.0f + erff(x * GELU_C));
}

// ---------------------------------------------------------------------------
// K1: asp_query partials. grid (B, ASL), 192 threads (float4 cols).
// ---------------------------------------------------------------------------
__global__ void aspq_part_kernel(const float* __restrict__ lh,
                                 const int* __restrict__ sep1,
                                 const int* __restrict__ sep2,
                                 float* __restrict__ aspp) {
    int b = blockIdx.x, z = blockIdx.y, t = threadIdx.x;
    int s1 = sep1[b], s2 = sep2[b];
    int lo, hi;
    if (s2 > s1 + 1) { lo = s1 + 1; hi = s2; } else { lo = 0; hi = 1; }
    const float* base = lh + ((size_t)b * S) * H + 4 * t;
    float4 a = {0.f, 0.f, 0.f, 0.f};
    for (int s = lo + z; s < hi; s += ASL) {
        float4 r = *(const float4*)(base + (size_t)s * H);
        a.x += r.x; a.y += r.y; a.z += r.z; a.w += r.w;
    }
    *(float4*)(aspp + (size_t)z * (B * H) + b * H + 4 * t) = a;
}

// ---------------------------------------------------------------------------
// K2: qu — merge aspq partials; q_h = aspq @ wq_h.T + bq_h; U = q_h @ wk_h.
// grid (B, NH), 256 threads. Block h==0 also writes merged aspq (for fuse).
// ---------------------------------------------------------------------------
__global__ void qu_kernel(const float* __restrict__ aspp,
                          const int* __restrict__ sep1,
                          const int* __restrict__ sep2,
                          const float* __restrict__ wq,
                          const float* __restrict__ bq,
                          const float* __restrict__ wk,
                          float* __restrict__ aspq,
                          float* __restrict__ U) {
    int b = blockIdx.x, h = blockIdx.y, t = threadIdx.x;
    int s1 = sep1[b], s2 = sep2[b];
    int lo, hi;
    if (s2 > s1 + 1) { lo = s1 + 1; hi = s2; } else { lo = 0; hi = 1; }
    float inv = 1.0f / (float)(hi - lo);
    __shared__ float aq[H];
    __shared__ float qh[DH];
    for (int c = t; c < H; c += 256) {
        float a = 0.f;
#pragma unroll
        for (int z = 0; z < ASL; ++z)
            a += aspp[(size_t)z * (B * H) + b * H + c];
        a *= inv;
        aq[c] = a;
        if (h == 0) aspq[b * H + c] = a;
    }
    __syncthreads();
    int wave = t >> 6, lane = t & 63;
#pragma unroll
    for (int i = 0; i < 24; ++i) {
        int d = wave * 24 + i;
        const float* wrow = wq + (size_t)(h * DH + d) * H;
        float a = 0.f;
#pragma unroll
        for (int j = 0; j < H / 64; ++j) a += wrow[lane + 64 * j] * aq[lane + 64 * j];
        for (int off = 32; off; off >>= 1) a += __shfl_xor(a, off);
        if (lane == 0) qh[d] = a + bq[h * DH + d];
    }
    __syncthreads();
    float u0 = 0.f, u1 = 0.f, u2 = 0.f;
    for (int d = 0; d < DH; ++d) {
        const float* wrow = wk + (size_t)(h * DH + d) * H;
        float qd = qh[d];
        u0 += qd * wrow[t];
        u1 += qd * wrow[t + 256];
        u2 += qd * wrow[t + 512];
    }
    float* Ub = U + ((size_t)b * NH + h) * H;
    Ub[t] = u0; Ub[t + 256] = u1; Ub[t + 512] = u2;
}

// ---------------------------------------------------------------------------
// K3: flash — wave-per-head online softmax + weighted V-sum, one lh pass.
// grid (B, NSL), 512 threads (8 waves). Slice z owns rows tlo+z+NSL*j.
// ---------------------------------------------------------------------------
__global__ __launch_bounds__(512) void flash_kernel(
        const float* __restrict__ lhg,
        const float* __restrict__ U,
        const int* __restrict__ sep1,
        float* __restrict__ Op,     // [NSL][B][NH][H]
        float* __restrict__ mlb) {  // [NSL][B][NH][2]
    int b = blockIdx.x, z = blockIdx.y, t = threadIdx.x;
    int wave = t >> 6, lane = t & 63;
    int s1 = sep1[b];
    int tlo = (s1 > 1) ? 1 : 0;
    int thi = (s1 > 1) ? s1 : 1;
    int span = thi - tlo;
    int nrows = (span > z) ? ((span - z - 1) / NSL + 1) : 0;

    __shared__ float lhs[FCH][H];   // 48 KB

    const float4* Uh = (const float4*)(U + ((size_t)b * NH + wave) * H);
    float4 u0 = Uh[lane], u1 = Uh[lane + 64], u2 = Uh[lane + 128];
    float4 O0 = {0.f, 0.f, 0.f, 0.f}, O1 = O0, O2 = O0;
    float m = -1e30f, l = 0.f;

    int rid = t >> 5;        // 0..15 (staging row)
    int cid = t & 31;        // 0..31 (staging col group)

    for (int j0 = 0; j0 < nrows; j0 += FCH) {
        int nv = min(FCH, nrows - j0);
        if (rid < nv) {
            int sg = tlo + z + NSL * (j0 + rid);
            const float4* row = (const float4*)(lhg + ((size_t)b * S + sg) * H);
            float4* dst = (float4*)lhs[rid];
#pragma unroll
            for (int k = 0; k < 6; ++k) dst[cid + 32 * k] = row[cid + 32 * k];
        }
        __syncthreads();
        for (int r = 0; r < nv; ++r) {
            const float4* xr = (const float4*)lhs[r];
            float4 x0 = xr[lane], x1 = xr[lane + 64], x2 = xr[lane + 128];
            float s = dot4(u0, x0) + dot4(u1, x1) + dot4(u2, x2);
            for (int off = 32; off; off >>= 1) s += __shfl_xor(s, off);
            s *= SCALE;
            if (s <= m) {            // common path: no rescale
                float p = __expf(s - m);
                l += p;
                O0.x += p * x0.x; O0.y += p * x0.y; O0.z += p * x0.z; O0.w += p * x0.w;
                O1.x += p * x1.x; O1.y += p * x1.y; O1.z += p * x1.z; O1.w += p * x1.w;
                O2.x += p * x2.x; O2.y += p * x2.y; O2.z += p * x2.z; O2.w += p * x2.w;
            } else {                 // max moved: rescale, p == 1
                float c = __expf(m - s);
                m = s;
                l = l * c + 1.0f;
                O0.x = O0.x * c + x0.x; O0.y = O0.y * c + x0.y;
                O0.z = O0.z * c + x0.z; O0.w = O0.w * c + x0.w;
                O1.x = O1.x * c + x1.x; O1.y = O1.y * c + x1.y;
                O1.z = O1.z * c + x1.z; O1.w = O1.w * c + x1.w;
                O2.x = O2.x * c + x2.x; O2.y = O2.y * c + x2.y;
                O2.z = O2.z * c + x2.z; O2.w = O2.w * c + x2.w;
            }
        }
        __syncthreads();
    }
    float4* Ob = (float4*)(Op + (((size_t)z * B + b) * NH + wave) * H);
    Ob[lane] = O0; Ob[lane + 64] = O1; Ob[lane + 128] = O2;
    if (lane == 0) {
        float* ml = mlb + ((size_t)z * B + b) * NH * 2;
        ml[2 * wave]     = m;
        ml[2 * wave + 1] = l;
    }
}

// ---------------------------------------------------------------------------
// K4: mergefuse — per-b block (512 thr):
//   merge flash slices -> wsum(LDS) -> ctx(LDS, +bv) -> cross(+out_b)
//   -> fused row [lh0 | cross | aspq | LN(aro)] (global + LDS) -> pol/aro.
// ---------------------------------------------------------------------------
__global__ __launch_bounds__(512) void mergefuse_kernel(
        const float* __restrict__ Op,
        const float* __restrict__ mlb,
        const float* __restrict__ wv,
        const float* __restrict__ bv,
        const float* __restrict__ out_w,
        const float* __restrict__ out_b,
        const float* __restrict__ lh,
        const float* __restrict__ aspq,
        const float* __restrict__ aro_f,
        const float* __restrict__ ln_g,
        const float* __restrict__ ln_b,
        const float* __restrict__ pol_w,
        const float* __restrict__ pol_b,
        const float* __restrict__ aro_w,
        const float* __restrict__ aro_b,
        float* __restrict__ fused,
        float* __restrict__ out) {
    int b = blockIdx.x, t = threadIdx.x;
    int wave = t >> 6, lane = t & 63;
    __shared__ float wsumS[NH * H];    // 24 KB
    __shared__ float ctxS[H];          // 3 KB
    __shared__ float fusedS[FPAD];     // 9.5 KB

    // phase 0: fused slots that don't depend on attention
    const float* lhb = lh + (size_t)b * S * H;
    for (int i = t; i < H; i += 512) {
        fusedS[i]          = lhb[i];
        fusedS[2 * H + i]  = aspq[b * H + i];
    }
    for (int i = FUSED + t; i < FPAD; i += 512) fusedS[i] = 0.f;
    if (t < 8) {
        const float* af = aro_f + b * 8;
        float mu = 0.f;
#pragma unroll
        for (int j = 0; j < 8; ++j) mu += af[j];
        mu *= 0.125f;
        float var = 0.f;
#pragma unroll
        for (int j = 0; j < 8; ++j) { float d = af[j] - mu; var += d * d; }
        var *= 0.125f;
        fusedS[3 * H + t] = (af[t] - mu) * rsqrtf(var + 1e-5f) * ln_g[t] + ln_b[t];
    }

    // phase 1: wave h merges its head's slices
    {
        int h = wave;
        float M = -1e30f;
#pragma unroll
        for (int z = 0; z < NSL; ++z)
            M = fmaxf(M, mlb[(((size_t)z * B + b) * NH + h) * 2]);
        float wzv[NSL], L = 0.f;
#pragma unroll
        for (int z = 0; z < NSL; ++z) {
            const float* ml = mlb + (((size_t)z * B + b) * NH + h) * 2;
            float e = __expf(ml[0] - M);
            wzv[z] = e;
            L += e * ml[1];
        }
        float Li = 1.0f / L;
        for (int c = lane; c < H; c += 64) {
            float a = 0.f;
#pragma unroll
            for (int z = 0; z < NSL; ++z)
                a += wzv[z] * Op[(((size_t)z * B + b) * NH + h) * H + c];
            wsumS[h * H + c] = a * Li;
        }
    }
    __syncthreads();

    // phase 2: ctx[o] = wv[o] . wsum_{o/96} + bv[o]; wave w owns o in [96w,96w+96)
    {
        const float4* ws4 = (const float4*)(wsumS + wave * H);
        float4 s0 = ws4[lane], s1 = ws4[lane + 64], s2 = ws4[lane + 128];
        for (int i = 0; i < 96; ++i) {
            int o = wave * 96 + i;
            const float4* wr = (const float4*)(wv + (size_t)o * H);
            float a = dot4(wr[lane], s0) + dot4(wr[lane + 64], s1)
                    + dot4(wr[lane + 128], s2);
            for (int off = 32; off; off >>= 1) a += __shfl_xor(a, off);
            if (lane == 0) ctxS[o] = a + bv[o];
        }
    }
    __syncthreads();

    // phase 3: cross[o] = out_w[o] . ctx + out_b[o] -> fusedS[H + o]
    {
        const float4* c4 = (const float4*)ctxS;
        float4 s0 = c4[lane], s1 = c4[lane + 64], s2 = c4[lane + 128];
        for (int i = 0; i < 96; ++i) {
            int o = wave * 96 + i;
            const float4* wr = (const float4*)(out_w + (size_t)o * H);
            float a = dot4(wr[lane], s0) + dot4(wr[lane + 64], s1)
                    + dot4(wr[lane + 128], s2);
            for (int off = 32; off; off >>= 1) a += __shfl_xor(a, off);
            if (lane == 0) fusedS[H + o] = a + out_b[o];
        }
    }
    __syncthreads();

    // phase 4: write fused row (float4) + pol/aro heads from LDS
    {
        const float4* fs4 = (const float4*)fusedS;
        float4* fg4 = (float4*)(fused + (size_t)b * FPAD);
        for (int i = t; i < FPAD / 4; i += 512) fg4[i] = fs4[i];
    }
    if (wave < 6) {
        int r = (wave < 3) ? wave : wave - 3;
        const float* w = (wave < 3) ? (pol_w + (size_t)r * FUSED)
                                    : (aro_w + (size_t)r * FUSED);
        float a = 0.f;
#pragma unroll
        for (int j = 0; j < 37; ++j) {
            int k = lane + 64 * j;
            if (k < FUSED) a += fusedS[k] * w[k];
        }
        for (int off = 32; off; off >>= 1) a += __shfl_xor(a, off);
        if (lane == 0) {
            if (wave < 3) out[256 + b * 3 + r] = a + pol_b[r];
            else          out[640 + b * 3 + r] = a + aro_b[r];
        }
    }
}

// ---------------------------------------------------------------------------
// Generic small fp32 GEMM, float4 loads, 32x32 tiles, z split-K.
// ---------------------------------------------------------------------------
template <int TAG, bool KCL>
__global__ void gemm_kernel(const float* __restrict__ A, int lda, int a_bs,
                            const float* __restrict__ W, int ldw, int w_bs,
                            float* __restrict__ C, int ldc, int c_bs,
                            int M, int N, int K, int kclamp) {
    A += (size_t)blockIdx.z * a_bs;
    W += (size_t)blockIdx.z * w_bs;
    C += (size_t)blockIdx.z * c_bs;
    int kcl = KCL ? (kclamp - (int)blockIdx.z * w_bs) : 0;
    int n0 = blockIdx.x * 32, m0 = blockIdx.y * 32;
    __shared__ float As[32][33];
    __shared__ float Ws[32][33];
    int t = threadIdx.x;
    int tx = t & 31, ty = t >> 5;
    int lr = t >> 3, lc = (t & 7) * 4;
    float acc[4] = {0.f, 0.f, 0.f, 0.f};
    for (int k0 = 0; k0 < K; k0 += 32) {
        {
            float4 a = *(const float4*)(A + (size_t)(m0 + lr) * lda + k0 + lc);
            As[lr][lc] = a.x; As[lr][lc + 1] = a.y;
            As[lr][lc + 2] = a.z; As[lr][lc + 3] = a.w;
        }
        {
            int kk = k0 + lc;
            if (KCL) kk = min(kk, kcl);
            float4 w = *(const float4*)(W + (size_t)(n0 + lr) * ldw + kk);
            Ws[lr][lc] = w.x; Ws[lr][lc + 1] = w.y;
            Ws[lr][lc + 2] = w.z; Ws[lr][lc + 3] = w.w;
        }
        __syncthreads();
#pragma unroll
        for (int kk = 0; kk < 32; ++kk) {
            float wv = Ws[tx][kk];
#pragma unroll
            for (int i = 0; i < 4; ++i)
                acc[i] += As[ty + 8 * i][kk] * wv;
        }
        __syncthreads();
    }
    int n = n0 + tx;
#pragma unroll
    for (int i = 0; i < 4; ++i) {
        int m = m0 + ty + 8 * i;
        C[(size_t)m * ldc + n] = acc[i];
    }
}

// ---------------------------------------------------------------------------
// K6: mlp2 — reduce hdn1 partials + gelu -> hs; h2 = gelu(hs@va_w2.T+b2);
// va = h2@va_w3.T+b3. grid B, 512 threads.
// ---------------------------------------------------------------------------
__global__ __launch_bounds__(512) void mlp2_kernel(
        const float* __restrict__ hdn1p,
        const float* __restrict__ va_b1,
        const float* __restrict__ va_w2,
        const float* __restrict__ va_b2,
        const float* __restrict__ va_w3,
        const float* __restrict__ va_b3,
        float* __restrict__ out) {
    int b = blockIdx.x, t = threadIdx.x;
    int wave = t >> 6, lane = t & 63;
    __shared__ float hsS[512];
    __shared__ float h2S[128];
    {
        float s = 0.f;
#pragma unroll
        for (int z = 0; z < KSPLIT; ++z)
            s += hdn1p[(size_t)z * (B * 512) + b * 512 + t];
        hsS[t] = gelu(s + va_b1[t]);
    }
    __syncthreads();
#pragma unroll
    for (int i = 0; i < 16; ++i) {
        int n = wave * 16 + i;
        float a = 0.f;
#pragma unroll
        for (int j = 0; j < 8; ++j) {
            int k = lane + 64 * j;
            a += hsS[k] * va_w2[(size_t)n * 512 + k];
        }
        for (int off = 32; off; off >>= 1) a += __shfl_xor(a, off);
        if (lane == 0) h2S[n] = gelu(a + va_b2[n]);
    }
    __syncthreads();
    if (wave < 2) {
        float a = h2S[lane] * va_w3[wave * 128 + lane]
                + h2S[lane + 64] * va_w3[wave * 128 + lane + 64];
        for (int off = 32; off; off >>= 1) a += __shfl_xor(a, off);
        if (lane == 0) out[b * 2 + wave] = a + va_b3[wave];
    }
}

// ---------------------------------------------------------------------------
extern "C" void kernel_launch(void* const* d_in, const int* in_sizes, int n_in,
                              void* d_out, int out_size, void* d_ws, size_t ws_size,
                              hipStream_t stream) {
    const float* lh    = (const float*)d_in[0];
    const float* aro_f = (const float*)d_in[1];
    const int*   sep1  = (const int*)d_in[2];
    const int*   sep2  = (const int*)d_in[3];
    const float* in_w  = (const float*)d_in[4];
    const float* in_b  = (const float*)d_in[5];
    const float* out_w = (const float*)d_in[6];
    const float* out_b = (const float*)d_in[7];
    const float* ln_g  = (const float*)d_in[8];
    const float* ln_b  = (const float*)d_in[9];
    const float* va_w1 = (const float*)d_in[10];
    const float* va_b1 = (const float*)d_in[11];
    const float* va_w2 = (const float*)d_in[12];
    const float* va_b2 = (const float*)d_in[13];
    const float* va_w3 = (const float*)d_in[14];
    const float* va_b3 = (const float*)d_in[15];
    const float* pol_w = (const float*)d_in[16];
    const float* pol_b = (const float*)d_in[17];
    const float* aro_w = (const float*)d_in[18];
    const float* aro_b = (const float*)d_in[19];
    float* out = (float*)d_out;

    float* ws = (float*)d_ws;
    float* aspp   = ws;                              // ASL*B*H
    float* aspq   = aspp + ASL * B * H;              // B*H
    float* Ubuf   = aspq + B * H;                    // B*NH*H
    float* Opb    = Ubuf + B * NH * H;               // NSL*B*NH*H
    float* mlbuf  = Opb + (size_t)NSL * B * NH * H;  // NSL*B*NH*2
    float* fusedb = mlbuf + NSL * B * NH * 2;        // B*FPAD
    float* hdn1p  = fusedb + B * FPAD;               // 19*B*512

    const float* wq = in_w;
    const float* wk = in_w + H * H;
    const float* wv = in_w + 2 * H * H;
    const float* bq = in_b;
    const float* bv = in_b + 2 * H;

    // 1) asp_query partials
    aspq_part_kernel<<<dim3(B, ASL), 192, 0, stream>>>(lh, sep1, sep2, aspp);
    // 2) qu: merge + q + U
    qu_kernel<<<dim3(B, NH), 256, 0, stream>>>(aspp, sep1, sep2, wq, bq, wk,
                                               aspq, Ubuf);
    // 3) flash (wave-per-head)
    flash_kernel<<<dim3(B, NSL), 512, 0, stream>>>(lh, Ubuf, sep1, Opb, mlbuf);
    // 4) mergefuse: merge + ctx + cross + fused + LN + pol/aro
    mergefuse_kernel<<<B, 512, 0, stream>>>(Opb, mlbuf, wv, bv, out_w, out_b,
                                            lh, aspq, aro_f, ln_g, ln_b,
                                            pol_w, pol_b, aro_w, aro_b,
                                            fusedb, out);
    // 5) hdn1 split-K partials (19 x 128)
    gemm_kernel<4, true><<<dim3(16, 4, KSPLIT), 256, 0, stream>>>(
        fusedb, FPAD, KCHUNK, va_w1, FUSED, KCHUNK,
        hdn1p, 512, B * 512, B, 512, KCHUNK, FUSED - 4);
    // 6) mlp2: reduce+gelu + hdn2 + va
    mlp2_kernel<<<B, 512, 0, stream>>>(hdn1p, va_b1, va_w2, va_b2,
                                       va_w3, va_b3, out);
}